// Round 18
// baseline (690.133 us; speedup 1.0000x reference)
//
#include <hip/hip_runtime.h>
#include <cstdint>
#include <cstddef>

#define TB 2
#define TS 2048
#define TD 4096
#define TH 16
#define THD 256
#define TROT 64
#define TM (TB*TS)

typedef __attribute__((ext_vector_type(8))) short bf16x8;
typedef __attribute__((ext_vector_type(4))) float f32x4;

#define LGKM0  asm volatile("s_waitcnt lgkmcnt(0)" ::: "memory")
#define VMCNT8 asm volatile("s_waitcnt vmcnt(8)" ::: "memory")
#define VMCNT4 asm volatile("s_waitcnt vmcnt(4)" ::: "memory")
#define VMCNT0 asm volatile("s_waitcnt vmcnt(0)" ::: "memory")
#define SBAR   __builtin_amdgcn_s_barrier()
#define SCHED0 __builtin_amdgcn_sched_barrier(0)
#define PRIO1  __builtin_amdgcn_s_setprio(1)
#define PRIO0  __builtin_amdgcn_s_setprio(0)

#if __has_builtin(__builtin_amdgcn_exp2f)
#define EXP2(x) __builtin_amdgcn_exp2f(x)
#else
#define EXP2(x) exp2f(x)
#endif

__device__ __forceinline__ unsigned short f2bf(float f) {
  union { float f; unsigned u; } v; v.f = f;
  return (unsigned short)((v.u + 0x7fffu + ((v.u >> 16) & 1u)) >> 16);
}

__device__ __forceinline__ void gld16(const void* g, void* l) {
  __builtin_amdgcn_global_load_lds(
      (const __attribute__((address_space(1))) unsigned int*)g,
      (__attribute__((address_space(3))) unsigned int*)l, 16, 0, 0);
}

// ---------------- fused fp32 -> bf16 convert (5 tensors, dst contiguous) ----
__global__ __launch_bounds__(256) void k_cvt5(
    const float* __restrict__ s0, const float* __restrict__ s1,
    const float* __restrict__ s2, const float* __restrict__ s3,
    const float* __restrict__ s4, unsigned short* __restrict__ dst) {
  int i = blockIdx.x * 256 + threadIdx.x;          // 5 * 2^22 chunks of 4 floats
  int tsel = i >> 22, il = i & 4194303;
  const float* s = tsel == 0 ? s0 : tsel == 1 ? s1 : tsel == 2 ? s2 : tsel == 3 ? s3 : s4;
  float4 v = reinterpret_cast<const float4*>(s)[il];
  ushort4 o;
  o.x = f2bf(v.x); o.y = f2bf(v.y); o.z = f2bf(v.z); o.w = f2bf(v.w);
  *reinterpret_cast<ushort4*>(dst + (size_t)i * 4) = o;
}

// ======== shared 8-phase main loop (BK=64, 256x256, 8 waves, 16x16x32) ======
// r14 minimal-barrier schedule (best measured): 4 barriers / 8 phases.
#define GSTG(SBUF, SAB, SHALF, SKOFS) { \
    const unsigned short* _s = (SAB) ? srcB : srcA; \
    const int _b = (SBUF)*32768 + (SAB)*16384 + (SHALF)*8192; \
    gld16(_s + (size_t)(SHALF)*128*TD + (SKOFS) + roff[0], &lds[_b + t*8]); \
    gld16(_s + (size_t)(SHALF)*128*TD + (SKOFS) + roff[1], &lds[_b + (512+t)*8]); }

#define GLD_AF(DST, BUF, QA) { \
    _Pragma("unroll") for (int m = 0; m < 4; ++m) \
    _Pragma("unroll") for (int kk = 0; kk < 2; ++kk) \
      DST[m][kk] = *(const bf16x8*)&lds[(BUF)*32768 + (QA)*8192 + ((wm*4+m)*2+kk)*512 + llo]; }

#define GLD_BQ(DST, BUF, QB) { \
    _Pragma("unroll") for (int n = 0; n < 2; ++n) \
    _Pragma("unroll") for (int kk = 0; kk < 2; ++kk) \
      DST[n][kk] = *(const bf16x8*)&lds[(BUF)*32768 + 16384 + (QB)*8192 + ((wn*2+n)*2+kk)*512 + llo]; }

#define GMF(AF, BQ, QA, QB) { \
    _Pragma("unroll") for (int kk = 0; kk < 2; ++kk) \
    _Pragma("unroll") for (int m = 0; m < 4; ++m) \
    _Pragma("unroll") for (int n = 0; n < 2; ++n) \
      acc[QA][QB][m][n] = __builtin_amdgcn_mfma_f32_16x16x32_bf16( \
          AF[m][kk], BQ[n][kk], acc[QA][QB][m][n], 0,0,0); }

#define GEMM_MAIN_LOOP \
  GSTG(0,0,0, 0);  SCHED0; \
  GSTG(0,1,0, 0);  SCHED0; \
  GSTG(0,0,1, 0);  SCHED0; \
  GSTG(0,1,1, 0);  SCHED0; \
  GSTG(1,0,0, 64); SCHED0; \
  GSTG(1,1,0, 64); SCHED0; \
  VMCNT4; SBAR; SCHED0; \
  for (int i2 = 0; i2 < NT/2; ++i2) { \
    const int k1c = (2*i2+1) * 64; \
    const int k0n = (2*i2+2 < NT ? 2*i2+2 : NT-1) * 64; \
    const int k1n = (2*i2+3 < NT ? 2*i2+3 : NT-1) * 64; \
    /* P1 */ \
    GLD_AF(afP, 0, 0); GLD_BQ(bqP, 0, 0); \
    GSTG(1,0,1, k1c); \
    LGKM0; SCHED0; \
    PRIO1; GLD_BQ(bqQ, 0, 1); GMF(afP, bqP, 0, 0); PRIO0; SCHED0; \
    /* P2 (end-barrier protects buf0 h0 reads vs restage) */ \
    GSTG(1,1,1, k1c); \
    LGKM0; SCHED0; \
    PRIO1; GLD_AF(afQ, 0, 1); GMF(afP, bqQ, 0, 1); PRIO0; \
    SBAR; SCHED0; \
    /* P3 */ \
    GSTG(0,0,0, k0n); \
    LGKM0; SCHED0; \
    PRIO1; GMF(afQ, bqP, 1, 0); PRIO0; SCHED0; \
    /* P4 (publish buf1) */ \
    GSTG(0,1,0, k0n); \
    VMCNT4; SBAR; \
    LGKM0; SCHED0; \
    PRIO1; GMF(afQ, bqQ, 1, 1); PRIO0; SCHED0; \
    /* P5 */ \
    GLD_AF(afP, 1, 0); GLD_BQ(bqP, 1, 0); \
    GSTG(0,0,1, k0n); \
    LGKM0; SCHED0; \
    PRIO1; GLD_BQ(bqQ, 1, 1); GMF(afP, bqP, 0, 0); PRIO0; SCHED0; \
    /* P6 (end-barrier) */ \
    GSTG(0,1,1, k0n); \
    LGKM0; SCHED0; \
    PRIO1; GLD_AF(afQ, 1, 1); GMF(afP, bqQ, 0, 1); PRIO0; \
    SBAR; SCHED0; \
    /* P7 */ \
    GSTG(1,0,0, k1n); \
    LGKM0; SCHED0; \
    PRIO1; GMF(afQ, bqP, 1, 0); PRIO0; SCHED0; \
    /* P8 (publish buf0') */ \
    GSTG(1,1,0, k1n); \
    VMCNT4; SBAR; \
    LGKM0; SCHED0; \
    PRIO1; GMF(afQ, bqQ, 1, 1); PRIO0; SCHED0; \
  }

#define GEMM_PREAMBLE \
  const int K = TD; \
  const int t = threadIdx.x; \
  const int w = t >> 6, l = t & 63, lr = l & 15, lh = l >> 4; \
  const int wm = w >> 2, wn = w & 3; \
  const int llo = lr * 32 + ((lh ^ ((lr >> 1) & 3)) * 8); \
  int roff[2]; \
  _Pragma("unroll") \
  for (int it = 0; it < 2; ++it) { \
    int c = it * 512 + t; \
    int rl = (c >> 2) & 15; \
    roff[it] = (16 * (c >> 7) + rl) * K + ((c >> 6) & 1) * 32 + ((c & 3) ^ ((rl >> 1) & 3)) * 8; \
  } \
  f32x4 acc[2][2][4][2]; \
  _Pragma("unroll") \
  for (int qa = 0; qa < 2; ++qa) \
  _Pragma("unroll") \
    for (int qb = 0; qb < 2; ++qb) \
  _Pragma("unroll") \
      for (int m = 0; m < 4; ++m) \
  _Pragma("unroll") \
        for (int n = 0; n < 2; ++n) acc[qa][qb][m][n] = 0.f; \
  bf16x8 afP[4][2], afQ[4][2], bqP[2][2], bqQ[2][2]; \
  const int NT = K / 64;

// ---------------- merged QKV GEMM: 768 blocks, W = [Wq|Wk|Wv] ----------------
__global__ __launch_bounds__(512, 1) void k_gqkv(
    const unsigned short* __restrict__ A, const unsigned short* __restrict__ W,
    unsigned short* __restrict__ Qo, unsigned short* __restrict__ Ko,
    unsigned short* __restrict__ Vo,
    const float* __restrict__ sinp, const float* __restrict__ cosp)
{
  extern __shared__ unsigned short lds[];   // 131072 B
  const int id = blockIdx.x;
  const int xcd = id & 7, kk_ = id >> 3;           // 96 blocks per XCD
  const int m0 = ((xcd & 1) * 8 + kk_ / 12) * 256; // m-idx 0..15
  const int n0 = ((xcd >> 1) * 12 + kk_ % 12) * 256; // n-idx 0..47

  GEMM_PREAMBLE
  const unsigned short* srcA = A + (size_t)m0 * K;
  const unsigned short* srcB = W + (size_t)n0 * K;

  GEMM_MAIN_LOOP

  VMCNT0;
  const int tsel = n0 >> 12;          // 0=Q, 1=K, 2=V (block-uniform)
  if (tsel == 2) {
    // V^T [B,H,HD,S] via LDS bounce; slab [64 cols][256+pad rows].
    SBAR;
    const int n0v = n0 - 8192;
    const int b = m0 >> 11, sbase = m0 & (TS - 1);
#pragma unroll
    for (int qb = 0; qb < 2; ++qb)
#pragma unroll
      for (int n = 0; n < 2; ++n) {
        __syncthreads();
#pragma unroll
        for (int qa = 0; qa < 2; ++qa)
#pragma unroll
          for (int m = 0; m < 4; ++m) {
            int lcol = wn * 16 + lr;
            int srow = qa * 128 + wm * 64 + m * 16 + lh * 4;
            ushort4 o;
            o.x = f2bf(acc[qa][qb][m][n][0]); o.y = f2bf(acc[qa][qb][m][n][1]);
            o.z = f2bf(acc[qa][qb][m][n][2]); o.w = f2bf(acc[qa][qb][m][n][3]);
            *(ushort4*)&lds[lcol * 268 + srow] = o;
          }
        __syncthreads();
#pragma unroll
        for (int rr = 0; rr < 4; ++rr) {
          int idx = rr * 512 + t;              // 2048 chunks: 64 cols x 32 x 16B
          int dl = idx >> 5, sc = (idx & 31) * 8;
          uint4 v = *(const uint4*)&lds[dl * 268 + sc];
          int d = n0v + qb * 128 + (dl >> 4) * 32 + n * 16 + (dl & 15);
          *(uint4*)(Vo + ((size_t)((b * TH + (d >> 8)) * THD + (d & 255))) * TS + sbase + sc) = v;
        }
      }
  } else {
    unsigned short* outp = tsel ? Ko : Qo;
    const int nbase = n0 & 4095;
#pragma unroll
    for (int qa = 0; qa < 2; ++qa)
#pragma unroll
      for (int qb = 0; qb < 2; ++qb)
#pragma unroll
        for (int m = 0; m < 4; ++m)
#pragma unroll
          for (int n = 0; n < 2; ++n)
#pragma unroll
            for (int r = 0; r < 4; ++r) {
              int row = m0 + qa * 128 + wm * 64 + m * 16 + lh * 4 + r;
              int col = nbase + qb * 128 + wn * 32 + n * 16 + lr;
              float x = acc[qa][qb][m][n][r];
              float part = __shfl_xor(x, 1, 64);     // col partner d^1 = lane l^1
              int s = row & (TS - 1), b = row >> 11;
              int h = col >> 8, d = col & 255;
              float val = x;
              if (d < TROT) {
                float cc = cosp[s * TROT + d], ss = sinp[s * TROT + d];
                val = x * cc + ((d & 1) ? part : -part) * ss;
              }
              outp[((size_t)(b * TH + h) * TS + s) * THD + d] = f2bf(val);
            }
  }
}

// ---------------- output-projection GEMM: fp32 out [M,N] ----------------
__global__ __launch_bounds__(512, 1) void k_gout(
    const unsigned short* __restrict__ A, const unsigned short* __restrict__ W,
    float* __restrict__ out)
{
  extern __shared__ unsigned short lds[];   // 131072 B
  const int id = blockIdx.x;
  const int xcd = id & 7, kk_ = id >> 3;            // 32 blocks per XCD
  const int m0 = ((xcd >> 1) * 4 + (kk_ >> 3)) * 256;  // m-idx 0..15
  const int n0 = ((xcd & 1) * 8 + (kk_ & 7)) * 256;    // n-idx 0..15

  GEMM_PREAMBLE
  const unsigned short* srcA = A + (size_t)m0 * K;
  const unsigned short* srcB = W + (size_t)n0 * K;

  GEMM_MAIN_LOOP

  VMCNT0;
#pragma unroll
  for (int qa = 0; qa < 2; ++qa)
#pragma unroll
    for (int qb = 0; qb < 2; ++qb)
#pragma unroll
      for (int m = 0; m < 4; ++m)
#pragma unroll
        for (int n = 0; n < 2; ++n)
#pragma unroll
          for (int r = 0; r < 4; ++r) {
            int row = m0 + qa * 128 + wm * 64 + m * 16 + lh * 4 + r;
            int col = n0 + qb * 128 + wn * 32 + n * 16 + lr;
            out[(size_t)row * TD + col] = acc[qa][qb][m][n][r];
          }
}

// ---------------- causal flash attention, QBLK=128, KVBLK=64 ----------------
// 8 waves / 512 threads; K/V staged once per 128 q-rows (halves staging work).
// LDS exactly 80KB -> 2 blocks/CU. log2-domain softmax, wave-uniform masking
// (diag iff tile tail exceeds the wave's SMALLEST row — r17 bugfix),
// balanced dispatch ordering (co-resident pair sums constant).
__global__ __launch_bounds__(512, 2) void k_fattn(
    const unsigned short* __restrict__ Qt, const unsigned short* __restrict__ Kt,
    const unsigned short* __restrict__ Vt, unsigned short* __restrict__ O)
{
  extern __shared__ unsigned short sh[];   // K 32KB | V 32KB | Ps 16KB
  const int t = threadIdx.x, w = t >> 6, l = t & 63, lr = l & 15, lh = l >> 4;
  const int bh = blockIdx.x;
  const int y = blockIdx.y;
  const int qb = (y < 8) ? (15 - y) : (y - 8);   // pair-balanced ordering
  const int q0 = qb * 128;
  const int jmax = 2 * qb + 1;
  const float SC = 0.0625f * 1.44269504f;        // 1/sqrt(HD) * log2(e)

  const unsigned short* kbase = Kt + (size_t)bh * TS * THD;
  const unsigned short* vbase = Vt + (size_t)bh * THD * TS;

  const int llo = lr * 32 + ((lh ^ ((lr >> 1) & 3)) * 8);

  int koff[4], voff[4];
#pragma unroll
  for (int it = 0; it < 4; ++it) {
    int c = it * 512 + t;
    int row = (c >> 2) & 15;
    int scc = (c & 3) ^ ((row >> 1) & 3);
    koff[it] = (((c >> 9) & 3) * 16 + row) * THD + ((c >> 6) & 7) * 32 + scc * 8;
    voff[it] = (((c >> 6) & 15) * 16 + row) * TS + ((c >> 10) & 1) * 32 + scc * 8;
  }

  bf16x8 qf[8];
  const unsigned short* qp = Qt + ((size_t)bh * TS + q0 + w * 16 + lr) * THD;
#pragma unroll
  for (int kk = 0; kk < 8; ++kk) qf[kk] = *(const bf16x8*)(qp + kk * 32 + lh * 8);

  f32x4 oacc[16];
#pragma unroll
  for (int i = 0; i < 16; ++i) oacc[i] = 0.f;
  float mrow[4] = {-__builtin_inff(), -__builtin_inff(), -__builtin_inff(), -__builtin_inff()};
  float lrow[4] = {0.f, 0.f, 0.f, 0.f};   // lane-partial denominators

#pragma unroll
  for (int it = 0; it < 4; ++it) gld16(kbase + koff[it], &sh[(it*512 + t) * 8]);
#pragma unroll
  for (int it = 0; it < 4; ++it) gld16(vbase + voff[it], &sh[16384 + (it*512 + t) * 8]);

  const int qw = q0 + w * 16;               // wave's first q-row
  const int psb = 32768 + w * 1024;         // Ps: [16][64] + 16B-granule XOR

  for (int j = 0; j <= jmax; ++j) {
    const bool nx = (j < jmax);
    const bool active = (j * 64) <= (qw + 15);   // wave has unmasked cols
    const bool diag   = (j * 64 + 63) > qw;      // tile tail exceeds SMALLEST row
    VMCNT4; SBAR; SCHED0;    // K(j) resident (V(j) 4 loads may remain)

    f32x4 sacc[4];
#pragma unroll
    for (int nt = 0; nt < 4; ++nt) sacc[nt] = 0.f;
    if (active) {
      PRIO1;
#pragma unroll
      for (int kk = 0; kk < 8; ++kk)
#pragma unroll
        for (int nt = 0; nt < 4; ++nt) {
          bf16x8 kf = *(const bf16x8*)&sh[(nt*8 + kk)*512 + llo];
          sacc[nt] = __builtin_amdgcn_mfma_f32_16x16x32_bf16(qf[kk], kf, sacc[nt], 0, 0, 0);
        }
      PRIO0;
      LGKM0;
    }
    SBAR; SCHED0;
    if (nx) {                // restage K(j+1) under softmax+PV
      const unsigned short* kj = kbase + (size_t)(j + 1) * 64 * THD;
#pragma unroll
      for (int it = 0; it < 4; ++it) gld16(kj + koff[it], &sh[(it*512 + t) * 8]);
    }

    if (active) {
      // ---- online softmax (log2 domain) ----
      float p[4][4];
      const int qrow0 = qw + lh * 4;
      if (diag) {
#pragma unroll
        for (int nt = 0; nt < 4; ++nt) {
          int kpos = j * 64 + nt * 16 + lr;
#pragma unroll
          for (int r = 0; r < 4; ++r) {
            float sv = sacc[nt][r] * SC;
            if (kpos > qrow0 + r) sv = -__builtin_inff();
            p[nt][r] = sv;
          }
        }
      } else {
#pragma unroll
        for (int nt = 0; nt < 4; ++nt)
#pragma unroll
          for (int r = 0; r < 4; ++r)
            p[nt][r] = sacc[nt][r] * SC;
      }
      float lmax[4];
#pragma unroll
      for (int r = 0; r < 4; ++r)
        lmax[r] = fmaxf(fmaxf(p[0][r], p[1][r]), fmaxf(p[2][r], p[3][r]));
      float g = fmaxf(fmaxf(lmax[0] - mrow[0], lmax[1] - mrow[1]),
                      fmaxf(lmax[2] - mrow[2], lmax[3] - mrow[3]));
      if (__any(g > 11.5416f)) {            // 8*log2(e): rare rescale path
        float tmax[4] = {lmax[0], lmax[1], lmax[2], lmax[3]};
#pragma unroll
        for (int off = 1; off < 16; off <<= 1)
#pragma unroll
          for (int r = 0; r < 4; ++r) tmax[r] = fmaxf(tmax[r], __shfl_xor(tmax[r], off, 64));
        float alpha[4];
#pragma unroll
        for (int r = 0; r < 4; ++r) {
          float mn = fmaxf(mrow[r], tmax[r]);
          alpha[r] = EXP2(mrow[r] - mn);
          mrow[r] = mn;
          lrow[r] *= alpha[r];
        }
#pragma unroll
        for (int i = 0; i < 16; ++i)
#pragma unroll
          for (int r = 0; r < 4; ++r) oacc[i][r] *= alpha[r];
      }
#pragma unroll
      for (int r = 0; r < 4; ++r) {
        float pe0 = EXP2(p[0][r] - mrow[r]);
        float pe1 = EXP2(p[1][r] - mrow[r]);
        float pe2 = EXP2(p[2][r] - mrow[r]);
        float pe3 = EXP2(p[3][r] - mrow[r]);
        p[0][r] = pe0; p[1][r] = pe1; p[2][r] = pe2; p[3][r] = pe3;
        lrow[r] += (pe0 + pe1) + (pe2 + pe3);
      }

      // P relayout: [16][64] wave-private, 16B-granule XOR swizzle
#pragma unroll
      for (int nt = 0; nt < 4; ++nt)
#pragma unroll
        for (int r = 0; r < 4; ++r) {
          int row = lh * 4 + r;
          sh[psb + row * 64 + ((nt * 16 + lr) ^ ((row & 7) * 8))] = f2bf(p[nt][r]);
        }
    }

    VMCNT4;                  // V(j) resident (K(j+1) loads may remain)
    SBAR; SCHED0;
    if (active) {
      bf16x8 pfr0 = *(const bf16x8*)&sh[psb + lr * 64 + ((lh * 8) ^ ((lr & 7) * 8))];
      bf16x8 pfr1 = *(const bf16x8*)&sh[psb + lr * 64 + (((32 + lh * 8)) ^ ((lr & 7) * 8))];
      PRIO1;
#pragma unroll
      for (int dt = 0; dt < 16; ++dt) {
        bf16x8 vf = *(const bf16x8*)&sh[16384 + dt*512 + llo];
        oacc[dt] = __builtin_amdgcn_mfma_f32_16x16x32_bf16(pfr0, vf, oacc[dt], 0, 0, 0);
      }
#pragma unroll
      for (int dt = 0; dt < 16; ++dt) {
        bf16x8 vf = *(const bf16x8*)&sh[16384 + (16 + dt)*512 + llo];
        oacc[dt] = __builtin_amdgcn_mfma_f32_16x16x32_bf16(pfr1, vf, oacc[dt], 0, 0, 0);
      }
      PRIO0;
      LGKM0;
    }
    SBAR; SCHED0;
    if (nx) {                // restage V(j+1)
      const unsigned short* vj = vbase + (size_t)(j + 1) * 64;
#pragma unroll
      for (int it = 0; it < 4; ++it) gld16(vj + voff[it], &sh[16384 + (it*512 + t) * 8]);
    }
  }
  VMCNT0;

  // epilogue: reduce lane-partial denominators once, then write O
#pragma unroll
  for (int off = 1; off < 16; off <<= 1)
#pragma unroll
    for (int r = 0; r < 4; ++r) lrow[r] += __shfl_xor(lrow[r], off, 64);

  const int b = bh >> 4, h = bh & 15;
  float inv[4];
#pragma unroll
  for (int r = 0; r < 4; ++r) inv[r] = 1.f / lrow[r];
#pragma unroll
  for (int dt = 0; dt < 16; ++dt)
#pragma unroll
    for (int r = 0; r < 4; ++r) {
      int s = q0 + w * 16 + lh * 4 + r;
      O[((size_t)(b * TS + s) * TH + h) * THD + dt * 16 + lr] = f2bf(oacc[dt][r] * inv[r]);
    }
}

// ---------------- launch ----------------
extern "C" void kernel_launch(void* const* d_in, const int* in_sizes, int n_in,
                              void* d_out, int out_size, void* d_ws, size_t ws_size,
                              hipStream_t stream) {
  const float* hs   = (const float*)d_in[0];
  const float* sinp = (const float*)d_in[1];
  const float* cosp = (const float*)d_in[2];
  const float* Wq   = (const float*)d_in[3];
  const float* Wk   = (const float*)d_in[4];
  const float* Wv   = (const float*)d_in[5];
  const float* Wo   = (const float*)d_in[6];

  const size_t NE = (size_t)TM * TD;
  const size_t BYTES = NE * 2;
  char* ws = (char*)d_ws;
  unsigned short* hsb = (unsigned short*)(ws + 0*BYTES);
  unsigned short* Wqb = (unsigned short*)(ws + 1*BYTES);  // [Wq|Wk|Wv] contiguous
  unsigned short* Wob = (unsigned short*)(ws + 4*BYTES);
  unsigned short* Qt  = (unsigned short*)(ws + 5*BYTES);  // [B,H,S,HD]
  unsigned short* Ktb = (unsigned short*)(ws + 6*BYTES);  // [B,H,S,HD]
  unsigned short* Vtb = (unsigned short*)(ws + 7*BYTES);  // [B,H,HD,S]
  unsigned short* Ob  = (unsigned short*)(ws + 8*BYTES);  // [B,S,H,HD] == [M,D]

  k_cvt5<<<81920, 256, 0, stream>>>(hs, Wq, Wk, Wv, Wo, hsb);

  k_gqkv<<<768, 512, 131072, stream>>>(hsb, Wqb, Qt, Ktb, Vtb, sinp, cosp);

  k_fattn<<<dim3(TB*TH, 16), 512, 81920, stream>>>(Qt, Ktb, Vtb, Ob);

  k_gout<<<256, 512, 131072, stream>>>(Ob, Wob, (float*)d_out);
}

// Round 19
// 672.798 us; speedup vs baseline: 1.0258x; 1.0258x over previous
//
#include <hip/hip_runtime.h>
#include <cstdint>
#include <cstddef>

#define TB 2
#define TS 2048
#define TD 4096
#define TH 16
#define THD 256
#define TROT 64
#define TM (TB*TS)

typedef __attribute__((ext_vector_type(8))) short bf16x8;
typedef __attribute__((ext_vector_type(4))) float f32x4;

#define LGKM0  asm volatile("s_waitcnt lgkmcnt(0)" ::: "memory")
#define VMCNT8 asm volatile("s_waitcnt vmcnt(8)" ::: "memory")
#define VMCNT4 asm volatile("s_waitcnt vmcnt(4)" ::: "memory")
#define VMCNT0 asm volatile("s_waitcnt vmcnt(0)" ::: "memory")
#define SBAR   __builtin_amdgcn_s_barrier()
#define SCHED0 __builtin_amdgcn_sched_barrier(0)
#define PRIO1  __builtin_amdgcn_s_setprio(1)
#define PRIO0  __builtin_amdgcn_s_setprio(0)

#if __has_builtin(__builtin_amdgcn_exp2f)
#define EXP2(x) __builtin_amdgcn_exp2f(x)
#else
#define EXP2(x) exp2f(x)
#endif

__device__ __forceinline__ unsigned short f2bf(float f) {
  union { float f; unsigned u; } v; v.f = f;
  return (unsigned short)((v.u + 0x7fffu + ((v.u >> 16) & 1u)) >> 16);
}

__device__ __forceinline__ void gld16(const void* g, void* l) {
  __builtin_amdgcn_global_load_lds(
      (const __attribute__((address_space(1))) unsigned int*)g,
      (__attribute__((address_space(3))) unsigned int*)l, 16, 0, 0);
}

// ---------------- fused fp32 -> bf16 convert (5 tensors, dst contiguous) ----
__global__ __launch_bounds__(256) void k_cvt5(
    const float* __restrict__ s0, const float* __restrict__ s1,
    const float* __restrict__ s2, const float* __restrict__ s3,
    const float* __restrict__ s4, unsigned short* __restrict__ dst) {
  int i = blockIdx.x * 256 + threadIdx.x;          // 5 * 2^22 chunks of 4 floats
  int tsel = i >> 22, il = i & 4194303;
  const float* s = tsel == 0 ? s0 : tsel == 1 ? s1 : tsel == 2 ? s2 : tsel == 3 ? s3 : s4;
  float4 v = reinterpret_cast<const float4*>(s)[il];
  ushort4 o;
  o.x = f2bf(v.x); o.y = f2bf(v.y); o.z = f2bf(v.z); o.w = f2bf(v.w);
  *reinterpret_cast<ushort4*>(dst + (size_t)i * 4) = o;
}

// ======== shared 8-phase main loop (BK=64, 256x256, 8 waves, 16x16x32) ======
// r14 minimal-barrier schedule (best measured): 4 barriers / 8 phases.
#define GSTG(SBUF, SAB, SHALF, SKOFS) { \
    const unsigned short* _s = (SAB) ? srcB : srcA; \
    const int _b = (SBUF)*32768 + (SAB)*16384 + (SHALF)*8192; \
    gld16(_s + (size_t)(SHALF)*128*TD + (SKOFS) + roff[0], &lds[_b + t*8]); \
    gld16(_s + (size_t)(SHALF)*128*TD + (SKOFS) + roff[1], &lds[_b + (512+t)*8]); }

#define GLD_AF(DST, BUF, QA) { \
    _Pragma("unroll") for (int m = 0; m < 4; ++m) \
    _Pragma("unroll") for (int kk = 0; kk < 2; ++kk) \
      DST[m][kk] = *(const bf16x8*)&lds[(BUF)*32768 + (QA)*8192 + ((wm*4+m)*2+kk)*512 + llo]; }

#define GLD_BQ(DST, BUF, QB) { \
    _Pragma("unroll") for (int n = 0; n < 2; ++n) \
    _Pragma("unroll") for (int kk = 0; kk < 2; ++kk) \
      DST[n][kk] = *(const bf16x8*)&lds[(BUF)*32768 + 16384 + (QB)*8192 + ((wn*2+n)*2+kk)*512 + llo]; }

#define GMF(AF, BQ, QA, QB) { \
    _Pragma("unroll") for (int kk = 0; kk < 2; ++kk) \
    _Pragma("unroll") for (int m = 0; m < 4; ++m) \
    _Pragma("unroll") for (int n = 0; n < 2; ++n) \
      acc[QA][QB][m][n] = __builtin_amdgcn_mfma_f32_16x16x32_bf16( \
          AF[m][kk], BQ[n][kk], acc[QA][QB][m][n], 0,0,0); }

#define GEMM_MAIN_LOOP \
  GSTG(0,0,0, 0);  SCHED0; \
  GSTG(0,1,0, 0);  SCHED0; \
  GSTG(0,0,1, 0);  SCHED0; \
  GSTG(0,1,1, 0);  SCHED0; \
  GSTG(1,0,0, 64); SCHED0; \
  GSTG(1,1,0, 64); SCHED0; \
  VMCNT4; SBAR; SCHED0; \
  for (int i2 = 0; i2 < NT/2; ++i2) { \
    const int k1c = (2*i2+1) * 64; \
    const int k0n = (2*i2+2 < NT ? 2*i2+2 : NT-1) * 64; \
    const int k1n = (2*i2+3 < NT ? 2*i2+3 : NT-1) * 64; \
    /* P1 */ \
    GLD_AF(afP, 0, 0); GLD_BQ(bqP, 0, 0); \
    GSTG(1,0,1, k1c); \
    LGKM0; SCHED0; \
    PRIO1; GLD_BQ(bqQ, 0, 1); GMF(afP, bqP, 0, 0); PRIO0; SCHED0; \
    /* P2 (end-barrier protects buf0 h0 reads vs restage) */ \
    GSTG(1,1,1, k1c); \
    LGKM0; SCHED0; \
    PRIO1; GLD_AF(afQ, 0, 1); GMF(afP, bqQ, 0, 1); PRIO0; \
    SBAR; SCHED0; \
    /* P3 */ \
    GSTG(0,0,0, k0n); \
    LGKM0; SCHED0; \
    PRIO1; GMF(afQ, bqP, 1, 0); PRIO0; SCHED0; \
    /* P4 (publish buf1) */ \
    GSTG(0,1,0, k0n); \
    VMCNT4; SBAR; \
    LGKM0; SCHED0; \
    PRIO1; GMF(afQ, bqQ, 1, 1); PRIO0; SCHED0; \
    /* P5 */ \
    GLD_AF(afP, 1, 0); GLD_BQ(bqP, 1, 0); \
    GSTG(0,0,1, k0n); \
    LGKM0; SCHED0; \
    PRIO1; GLD_BQ(bqQ, 1, 1); GMF(afP, bqP, 0, 0); PRIO0; SCHED0; \
    /* P6 (end-barrier) */ \
    GSTG(0,1,1, k0n); \
    LGKM0; SCHED0; \
    PRIO1; GLD_AF(afQ, 1, 1); GMF(afP, bqQ, 0, 1); PRIO0; \
    SBAR; SCHED0; \
    /* P7 */ \
    GSTG(1,0,0, k1n); \
    LGKM0; SCHED0; \
    PRIO1; GMF(afQ, bqP, 1, 0); PRIO0; SCHED0; \
    /* P8 (publish buf0') */ \
    GSTG(1,1,0, k1n); \
    VMCNT4; SBAR; \
    LGKM0; SCHED0; \
    PRIO1; GMF(afQ, bqQ, 1, 1); PRIO0; SCHED0; \
  }

#define GEMM_PREAMBLE \
  const int K = TD; \
  const int t = threadIdx.x; \
  const int w = t >> 6, l = t & 63, lr = l & 15, lh = l >> 4; \
  const int wm = w >> 2, wn = w & 3; \
  const int llo = lr * 32 + ((lh ^ ((lr >> 1) & 3)) * 8); \
  int roff[2]; \
  _Pragma("unroll") \
  for (int it = 0; it < 2; ++it) { \
    int c = it * 512 + t; \
    int rl = (c >> 2) & 15; \
    roff[it] = (16 * (c >> 7) + rl) * K + ((c >> 6) & 1) * 32 + ((c & 3) ^ ((rl >> 1) & 3)) * 8; \
  } \
  f32x4 acc[2][2][4][2]; \
  _Pragma("unroll") \
  for (int qa = 0; qa < 2; ++qa) \
  _Pragma("unroll") \
    for (int qb = 0; qb < 2; ++qb) \
  _Pragma("unroll") \
      for (int m = 0; m < 4; ++m) \
  _Pragma("unroll") \
        for (int n = 0; n < 2; ++n) acc[qa][qb][m][n] = 0.f; \
  bf16x8 afP[4][2], afQ[4][2], bqP[2][2], bqQ[2][2]; \
  const int NT = K / 64;

// ---------------- merged QKV GEMM: 768 blocks, W = [Wq|Wk|Wv] ----------------
__global__ __launch_bounds__(512, 1) void k_gqkv(
    const unsigned short* __restrict__ A, const unsigned short* __restrict__ W,
    unsigned short* __restrict__ Qo, unsigned short* __restrict__ Ko,
    unsigned short* __restrict__ Vo,
    const float* __restrict__ sinp, const float* __restrict__ cosp)
{
  extern __shared__ unsigned short lds[];   // 131072 B
  const int id = blockIdx.x;
  const int xcd = id & 7, kk_ = id >> 3;           // 96 blocks per XCD
  const int m0 = ((xcd & 1) * 8 + kk_ / 12) * 256; // m-idx 0..15
  const int n0 = ((xcd >> 1) * 12 + kk_ % 12) * 256; // n-idx 0..47

  GEMM_PREAMBLE
  const unsigned short* srcA = A + (size_t)m0 * K;
  const unsigned short* srcB = W + (size_t)n0 * K;

  GEMM_MAIN_LOOP

  VMCNT0;
  const int tsel = n0 >> 12;          // 0=Q, 1=K, 2=V (block-uniform)
  if (tsel == 2) {
    // V^T [B,H,HD,S] via LDS bounce; slab [64 cols][256+pad rows].
    SBAR;
    const int n0v = n0 - 8192;
    const int b = m0 >> 11, sbase = m0 & (TS - 1);
#pragma unroll
    for (int qb = 0; qb < 2; ++qb)
#pragma unroll
      for (int n = 0; n < 2; ++n) {
        __syncthreads();
#pragma unroll
        for (int qa = 0; qa < 2; ++qa)
#pragma unroll
          for (int m = 0; m < 4; ++m) {
            int lcol = wn * 16 + lr;
            int srow = qa * 128 + wm * 64 + m * 16 + lh * 4;
            ushort4 o;
            o.x = f2bf(acc[qa][qb][m][n][0]); o.y = f2bf(acc[qa][qb][m][n][1]);
            o.z = f2bf(acc[qa][qb][m][n][2]); o.w = f2bf(acc[qa][qb][m][n][3]);
            *(ushort4*)&lds[lcol * 268 + srow] = o;
          }
        __syncthreads();
#pragma unroll
        for (int rr = 0; rr < 4; ++rr) {
          int idx = rr * 512 + t;              // 2048 chunks: 64 cols x 32 x 16B
          int dl = idx >> 5, sc = (idx & 31) * 8;
          uint4 v = *(const uint4*)&lds[dl * 268 + sc];
          int d = n0v + qb * 128 + (dl >> 4) * 32 + n * 16 + (dl & 15);
          *(uint4*)(Vo + ((size_t)((b * TH + (d >> 8)) * THD + (d & 255))) * TS + sbase + sc) = v;
        }
      }
  } else {
    unsigned short* outp = tsel ? Ko : Qo;
    const int nbase = n0 & 4095;
#pragma unroll
    for (int qa = 0; qa < 2; ++qa)
#pragma unroll
      for (int qb = 0; qb < 2; ++qb)
#pragma unroll
        for (int m = 0; m < 4; ++m)
#pragma unroll
          for (int n = 0; n < 2; ++n)
#pragma unroll
            for (int r = 0; r < 4; ++r) {
              int row = m0 + qa * 128 + wm * 64 + m * 16 + lh * 4 + r;
              int col = nbase + qb * 128 + wn * 32 + n * 16 + lr;
              float x = acc[qa][qb][m][n][r];
              float part = __shfl_xor(x, 1, 64);     // col partner d^1 = lane l^1
              int s = row & (TS - 1), b = row >> 11;
              int h = col >> 8, d = col & 255;
              float val = x;
              if (d < TROT) {
                float cc = cosp[s * TROT + d], ss = sinp[s * TROT + d];
                val = x * cc + ((d & 1) ? part : -part) * ss;
              }
              outp[((size_t)(b * TH + h) * TS + s) * THD + d] = f2bf(val);
            }
  }
}

// ---------------- output-projection GEMM: fp32 out [M,N] ----------------
__global__ __launch_bounds__(512, 1) void k_gout(
    const unsigned short* __restrict__ A, const unsigned short* __restrict__ W,
    float* __restrict__ out)
{
  extern __shared__ unsigned short lds[];   // 131072 B
  const int id = blockIdx.x;
  const int xcd = id & 7, kk_ = id >> 3;            // 32 blocks per XCD
  const int m0 = ((xcd >> 1) * 4 + (kk_ >> 3)) * 256;  // m-idx 0..15
  const int n0 = ((xcd & 1) * 8 + (kk_ & 7)) * 256;    // n-idx 0..15

  GEMM_PREAMBLE
  const unsigned short* srcA = A + (size_t)m0 * K;
  const unsigned short* srcB = W + (size_t)n0 * K;

  GEMM_MAIN_LOOP

  VMCNT0;
#pragma unroll
  for (int qa = 0; qa < 2; ++qa)
#pragma unroll
    for (int qb = 0; qb < 2; ++qb)
#pragma unroll
      for (int m = 0; m < 4; ++m)
#pragma unroll
        for (int n = 0; n < 2; ++n)
#pragma unroll
          for (int r = 0; r < 4; ++r) {
            int row = m0 + qa * 128 + wm * 64 + m * 16 + lh * 4 + r;
            int col = n0 + qb * 128 + wn * 32 + n * 16 + lr;
            out[(size_t)row * TD + col] = acc[qa][qb][m][n][r];
          }
}

// ---------------- causal flash attention, KVBLK=64 (r16 best-measured) ------
// log2-domain softmax (v_exp_f32 native) + last-tile-only causal masking.
__global__ __launch_bounds__(256, 2) void k_fattn(
    const unsigned short* __restrict__ Qt, const unsigned short* __restrict__ Kt,
    const unsigned short* __restrict__ Vt, unsigned short* __restrict__ O)
{
  extern __shared__ unsigned short sh[];   // K 32KB | V 32KB | Ps 9KB
  const int t = threadIdx.x, w = t >> 6, l = t & 63, lr = l & 15, lh = l >> 4;
  const int bh = blockIdx.x;
  const int qb = (gridDim.y - 1) - blockIdx.y;   // LPT: heaviest first
  const int q0 = qb * 64;
  const int jmax = qb;
  const float SC = 0.0625f * 1.44269504f;        // 1/sqrt(HD) * log2(e)

  const unsigned short* kbase = Kt + (size_t)bh * TS * THD;
  const unsigned short* vbase = Vt + (size_t)bh * THD * TS;

  const int llo = lr * 32 + ((lh ^ ((lr >> 1) & 3)) * 8);

  int koff[8], voff[8];
#pragma unroll
  for (int it = 0; it < 8; ++it) {
    int c = it * 256 + t;
    int row = (c >> 2) & 15;
    int scc = (c & 3) ^ ((row >> 1) & 3);
    koff[it] = (((c >> 9) & 3) * 16 + row) * THD + ((c >> 6) & 7) * 32 + scc * 8;
    voff[it] = (((c >> 6) & 15) * 16 + row) * TS + ((c >> 10) & 1) * 32 + scc * 8;
  }

  bf16x8 qf[8];
  const unsigned short* qp = Qt + ((size_t)bh * TS + q0 + w * 16 + lr) * THD;
#pragma unroll
  for (int kk = 0; kk < 8; ++kk) qf[kk] = *(const bf16x8*)(qp + kk * 32 + lh * 8);

  f32x4 oacc[16];
#pragma unroll
  for (int i = 0; i < 16; ++i) oacc[i] = 0.f;
  float mrow[4] = {-__builtin_inff(), -__builtin_inff(), -__builtin_inff(), -__builtin_inff()};
  float lrow[4] = {0.f, 0.f, 0.f, 0.f};   // lane-partial denominators

#pragma unroll
  for (int it = 0; it < 8; ++it) gld16(kbase + koff[it], &sh[(it*256 + t) * 8]);
#pragma unroll
  for (int it = 0; it < 8; ++it) gld16(vbase + voff[it], &sh[16384 + (it*256 + t) * 8]);

  for (int j = 0; j <= jmax; ++j) {
    const bool nx = (j < jmax);
    VMCNT8; SBAR; SCHED0;

    f32x4 sacc[4];
#pragma unroll
    for (int nt = 0; nt < 4; ++nt) sacc[nt] = 0.f;
    PRIO1;
#pragma unroll
    for (int kk = 0; kk < 8; ++kk)
#pragma unroll
      for (int nt = 0; nt < 4; ++nt) {
        bf16x8 kf = *(const bf16x8*)&sh[(nt*8 + kk)*512 + llo];
        sacc[nt] = __builtin_amdgcn_mfma_f32_16x16x32_bf16(qf[kk], kf, sacc[nt], 0, 0, 0);
      }
    PRIO0;
    LGKM0; SBAR; SCHED0;
    if (nx) {
      const unsigned short* kj = kbase + (size_t)(j + 1) * 64 * THD;
#pragma unroll
      for (int it = 0; it < 8; ++it) gld16(kj + koff[it], &sh[(it*256 + t) * 8]);
    }

    // ---- online softmax (log2 domain; mask only on diagonal tile) ----
    float p[4][4];
    const int qrow0 = q0 + w * 16 + lh * 4;
    if (j == jmax) {
#pragma unroll
      for (int nt = 0; nt < 4; ++nt) {
        int kpos = j * 64 + nt * 16 + lr;
#pragma unroll
        for (int r = 0; r < 4; ++r) {
          float sv = sacc[nt][r] * SC;
          if (kpos > qrow0 + r) sv = -__builtin_inff();
          p[nt][r] = sv;
        }
      }
    } else {
#pragma unroll
      for (int nt = 0; nt < 4; ++nt)
#pragma unroll
        for (int r = 0; r < 4; ++r)
          p[nt][r] = sacc[nt][r] * SC;
    }
    float lmax[4];
#pragma unroll
    for (int r = 0; r < 4; ++r)
      lmax[r] = fmaxf(fmaxf(p[0][r], p[1][r]), fmaxf(p[2][r], p[3][r]));
    float g = fmaxf(fmaxf(lmax[0] - mrow[0], lmax[1] - mrow[1]),
                    fmaxf(lmax[2] - mrow[2], lmax[3] - mrow[3]));
    if (__any(g > 11.5416f)) {              // 8 * log2(e): rare rescale path
      float tmax[4] = {lmax[0], lmax[1], lmax[2], lmax[3]};
#pragma unroll
      for (int off = 1; off < 16; off <<= 1)
#pragma unroll
        for (int r = 0; r < 4; ++r) tmax[r] = fmaxf(tmax[r], __shfl_xor(tmax[r], off, 64));
      float alpha[4];
#pragma unroll
      for (int r = 0; r < 4; ++r) {
        float mn = fmaxf(mrow[r], tmax[r]);
        alpha[r] = EXP2(mrow[r] - mn);
        mrow[r] = mn;
        lrow[r] *= alpha[r];
      }
#pragma unroll
      for (int i = 0; i < 16; ++i)
#pragma unroll
        for (int r = 0; r < 4; ++r) oacc[i][r] *= alpha[r];
    }
#pragma unroll
    for (int r = 0; r < 4; ++r) {
      float pe0 = EXP2(p[0][r] - mrow[r]);
      float pe1 = EXP2(p[1][r] - mrow[r]);
      float pe2 = EXP2(p[2][r] - mrow[r]);
      float pe3 = EXP2(p[3][r] - mrow[r]);
      p[0][r] = pe0; p[1][r] = pe1; p[2][r] = pe2; p[3][r] = pe3;
      lrow[r] += (pe0 + pe1) + (pe2 + pe3);
    }

    const int wb = 32768 + w * 1152;
#pragma unroll
    for (int nt = 0; nt < 4; ++nt)
#pragma unroll
      for (int r = 0; r < 4; ++r)
        sh[wb + (lh*4 + r)*72 + nt*16 + lr] = f2bf(p[nt][r]);
    bf16x8 pfr0 = *(const bf16x8*)&sh[wb + lr*72 + lh*8];
    bf16x8 pfr1 = *(const bf16x8*)&sh[wb + lr*72 + 32 + lh*8];

    if (nx) { VMCNT8; } else { VMCNT0; }
    SBAR; SCHED0;
    PRIO1;
#pragma unroll
    for (int dt = 0; dt < 16; ++dt) {
      bf16x8 vf = *(const bf16x8*)&sh[16384 + dt*512 + llo];
      oacc[dt] = __builtin_amdgcn_mfma_f32_16x16x32_bf16(pfr0, vf, oacc[dt], 0, 0, 0);
    }
#pragma unroll
    for (int dt = 0; dt < 16; ++dt) {
      bf16x8 vf = *(const bf16x8*)&sh[16384 + (16 + dt)*512 + llo];
      oacc[dt] = __builtin_amdgcn_mfma_f32_16x16x32_bf16(pfr1, vf, oacc[dt], 0, 0, 0);
    }
    PRIO0;
    LGKM0; SBAR; SCHED0;
    if (nx) {
      const unsigned short* vj = vbase + (size_t)(j + 1) * 64;
#pragma unroll
      for (int it = 0; it < 8; ++it) gld16(vj + voff[it], &sh[16384 + (it*256 + t) * 8]);
    }
  }

  // epilogue: reduce lane-partial denominators once, then write O
#pragma unroll
  for (int off = 1; off < 16; off <<= 1)
#pragma unroll
    for (int r = 0; r < 4; ++r) lrow[r] += __shfl_xor(lrow[r], off, 64);

  const int b = bh >> 4, h = bh & 15;
  float inv[4];
#pragma unroll
  for (int r = 0; r < 4; ++r) inv[r] = 1.f / lrow[r];
#pragma unroll
  for (int dt = 0; dt < 16; ++dt)
#pragma unroll
    for (int r = 0; r < 4; ++r) {
      int s = q0 + w * 16 + lh * 4 + r;
      O[((size_t)(b * TS + s) * TH + h) * THD + dt * 16 + lr] = f2bf(oacc[dt][r] * inv[r]);
    }
}

// ---------------- launch ----------------
extern "C" void kernel_launch(void* const* d_in, const int* in_sizes, int n_in,
                              void* d_out, int out_size, void* d_ws, size_t ws_size,
                              hipStream_t stream) {
  const float* hs   = (const float*)d_in[0];
  const float* sinp = (const float*)d_in[1];
  const float* cosp = (const float*)d_in[2];
  const float* Wq   = (const float*)d_in[3];
  const float* Wk   = (const float*)d_in[4];
  const float* Wv   = (const float*)d_in[5];
  const float* Wo   = (const float*)d_in[6];

  const size_t NE = (size_t)TM * TD;
  const size_t BYTES = NE * 2;
  char* ws = (char*)d_ws;
  unsigned short* hsb = (unsigned short*)(ws + 0*BYTES);
  unsigned short* Wqb = (unsigned short*)(ws + 1*BYTES);  // [Wq|Wk|Wv] contiguous
  unsigned short* Wob = (unsigned short*)(ws + 4*BYTES);
  unsigned short* Qt  = (unsigned short*)(ws + 5*BYTES);  // [B,H,S,HD]
  unsigned short* Ktb = (unsigned short*)(ws + 6*BYTES);  // [B,H,S,HD]
  unsigned short* Vtb = (unsigned short*)(ws + 7*BYTES);  // [B,H,HD,S]
  unsigned short* Ob  = (unsigned short*)(ws + 8*BYTES);  // [B,S,H,HD] == [M,D]

  k_cvt5<<<81920, 256, 0, stream>>>(hs, Wq, Wk, Wv, Wo, hsb);

  k_gqkv<<<768, 512, 131072, stream>>>(hsb, Wqb, Qt, Ktb, Vtb, sinp, cosp);

  k_fattn<<<dim3(TB*TH, TS/64), 256, 74752, stream>>>(Qt, Ktb, Vtb, Ob);

  k_gout<<<256, 512, 131072, stream>>>(Ob, Wob, (float*)d_out);
}

// Round 20
// 669.685 us; speedup vs baseline: 1.0305x; 1.0046x over previous
//
#include <hip/hip_runtime.h>
#include <cstdint>
#include <cstddef>

#define TB 2
#define TS 2048
#define TD 4096
#define TH 16
#define THD 256
#define TROT 64
#define TM (TB*TS)

typedef __attribute__((ext_vector_type(8))) short bf16x8;
typedef __attribute__((ext_vector_type(4))) float f32x4;

#define LGKM0  asm volatile("s_waitcnt lgkmcnt(0)" ::: "memory")
#define VMCNT8 asm volatile("s_waitcnt vmcnt(8)" ::: "memory")
#define VMCNT4 asm volatile("s_waitcnt vmcnt(4)" ::: "memory")
#define VMCNT0 asm volatile("s_waitcnt vmcnt(0)" ::: "memory")
#define SBAR   __builtin_amdgcn_s_barrier()
#define SCHED0 __builtin_amdgcn_sched_barrier(0)
#define PRIO1  __builtin_amdgcn_s_setprio(1)
#define PRIO0  __builtin_amdgcn_s_setprio(0)

#if __has_builtin(__builtin_amdgcn_exp2f)
#define EXP2(x) __builtin_amdgcn_exp2f(x)
#else
#define EXP2(x) exp2f(x)
#endif

__device__ __forceinline__ unsigned short f2bf(float f) {
  union { float f; unsigned u; } v; v.f = f;
  return (unsigned short)((v.u + 0x7fffu + ((v.u >> 16) & 1u)) >> 16);
}

__device__ __forceinline__ void gld16(const void* g, void* l) {
  __builtin_amdgcn_global_load_lds(
      (const __attribute__((address_space(1))) unsigned int*)g,
      (__attribute__((address_space(3))) unsigned int*)l, 16, 0, 0);
}

// ---------------- fused fp32 -> bf16 convert (5 tensors, dst contiguous) ----
__global__ __launch_bounds__(256) void k_cvt5(
    const float* __restrict__ s0, const float* __restrict__ s1,
    const float* __restrict__ s2, const float* __restrict__ s3,
    const float* __restrict__ s4, unsigned short* __restrict__ dst) {
  int i = blockIdx.x * 256 + threadIdx.x;          // 5 * 2^22 chunks of 4 floats
  int tsel = i >> 22, il = i & 4194303;
  const float* s = tsel == 0 ? s0 : tsel == 1 ? s1 : tsel == 2 ? s2 : tsel == 3 ? s3 : s4;
  float4 v = reinterpret_cast<const float4*>(s)[il];
  ushort4 o;
  o.x = f2bf(v.x); o.y = f2bf(v.y); o.z = f2bf(v.z); o.w = f2bf(v.w);
  *reinterpret_cast<ushort4*>(dst + (size_t)i * 4) = o;
}

// ======== shared 8-phase main loop (BK=64, 256x256, 8 waves, 16x16x32) ======
// r14 minimal-barrier schedule + r20 change: NO explicit lgkmcnt(0) drains in
// the phase bodies — compiler emits fine-grained counted lgkmcnt before each
// consuming MFMA (m97 behavior), overlapping read-completion with MFMA issue.
// SCHED0 after each barrier still pins reads below buffer publication.
#define GSTG(SBUF, SAB, SHALF, SKOFS) { \
    const unsigned short* _s = (SAB) ? srcB : srcA; \
    const int _b = (SBUF)*32768 + (SAB)*16384 + (SHALF)*8192; \
    gld16(_s + (size_t)(SHALF)*128*TD + (SKOFS) + roff[0], &lds[_b + t*8]); \
    gld16(_s + (size_t)(SHALF)*128*TD + (SKOFS) + roff[1], &lds[_b + (512+t)*8]); }

#define GLD_AF(DST, BUF, QA) { \
    _Pragma("unroll") for (int m = 0; m < 4; ++m) \
    _Pragma("unroll") for (int kk = 0; kk < 2; ++kk) \
      DST[m][kk] = *(const bf16x8*)&lds[(BUF)*32768 + (QA)*8192 + ((wm*4+m)*2+kk)*512 + llo]; }

#define GLD_BQ(DST, BUF, QB) { \
    _Pragma("unroll") for (int n = 0; n < 2; ++n) \
    _Pragma("unroll") for (int kk = 0; kk < 2; ++kk) \
      DST[n][kk] = *(const bf16x8*)&lds[(BUF)*32768 + 16384 + (QB)*8192 + ((wn*2+n)*2+kk)*512 + llo]; }

#define GMF(AF, BQ, QA, QB) { \
    _Pragma("unroll") for (int kk = 0; kk < 2; ++kk) \
    _Pragma("unroll") for (int m = 0; m < 4; ++m) \
    _Pragma("unroll") for (int n = 0; n < 2; ++n) \
      acc[QA][QB][m][n] = __builtin_amdgcn_mfma_f32_16x16x32_bf16( \
          AF[m][kk], BQ[n][kk], acc[QA][QB][m][n], 0,0,0); }

#define GEMM_MAIN_LOOP \
  GSTG(0,0,0, 0);  SCHED0; \
  GSTG(0,1,0, 0);  SCHED0; \
  GSTG(0,0,1, 0);  SCHED0; \
  GSTG(0,1,1, 0);  SCHED0; \
  GSTG(1,0,0, 64); SCHED0; \
  GSTG(1,1,0, 64); SCHED0; \
  VMCNT4; SBAR; SCHED0; \
  for (int i2 = 0; i2 < NT/2; ++i2) { \
    const int k1c = (2*i2+1) * 64; \
    const int k0n = (2*i2+2 < NT ? 2*i2+2 : NT-1) * 64; \
    const int k1n = (2*i2+3 < NT ? 2*i2+3 : NT-1) * 64; \
    /* P1 */ \
    GLD_AF(afP, 0, 0); GLD_BQ(bqP, 0, 0); \
    GSTG(1,0,1, k1c); \
    SCHED0; \
    PRIO1; GLD_BQ(bqQ, 0, 1); GMF(afP, bqP, 0, 0); PRIO0; SCHED0; \
    /* P2 (end-barrier protects buf0 h0 reads vs restage) */ \
    GSTG(1,1,1, k1c); \
    SCHED0; \
    PRIO1; GLD_AF(afQ, 0, 1); GMF(afP, bqQ, 0, 1); PRIO0; \
    SBAR; SCHED0; \
    /* P3 */ \
    GSTG(0,0,0, k0n); \
    SCHED0; \
    PRIO1; GMF(afQ, bqP, 1, 0); PRIO0; SCHED0; \
    /* P4 (publish buf1) */ \
    GSTG(0,1,0, k0n); \
    VMCNT4; SBAR; \
    SCHED0; \
    PRIO1; GMF(afQ, bqQ, 1, 1); PRIO0; SCHED0; \
    /* P5 */ \
    GLD_AF(afP, 1, 0); GLD_BQ(bqP, 1, 0); \
    GSTG(0,0,1, k0n); \
    SCHED0; \
    PRIO1; GLD_BQ(bqQ, 1, 1); GMF(afP, bqP, 0, 0); PRIO0; SCHED0; \
    /* P6 (end-barrier) */ \
    GSTG(0,1,1, k0n); \
    SCHED0; \
    PRIO1; GLD_AF(afQ, 1, 1); GMF(afP, bqQ, 0, 1); PRIO0; \
    SBAR; SCHED0; \
    /* P7 */ \
    GSTG(1,0,0, k1n); \
    SCHED0; \
    PRIO1; GMF(afQ, bqP, 1, 0); PRIO0; SCHED0; \
    /* P8 (publish buf0') */ \
    GSTG(1,1,0, k1n); \
    VMCNT4; SBAR; \
    SCHED0; \
    PRIO1; GMF(afQ, bqQ, 1, 1); PRIO0; SCHED0; \
  }

#define GEMM_PREAMBLE \
  const int K = TD; \
  const int t = threadIdx.x; \
  const int w = t >> 6, l = t & 63, lr = l & 15, lh = l >> 4; \
  const int wm = w >> 2, wn = w & 3; \
  const int llo = lr * 32 + ((lh ^ ((lr >> 1) & 3)) * 8); \
  int roff[2]; \
  _Pragma("unroll") \
  for (int it = 0; it < 2; ++it) { \
    int c = it * 512 + t; \
    int rl = (c >> 2) & 15; \
    roff[it] = (16 * (c >> 7) + rl) * K + ((c >> 6) & 1) * 32 + ((c & 3) ^ ((rl >> 1) & 3)) * 8; \
  } \
  f32x4 acc[2][2][4][2]; \
  _Pragma("unroll") \
  for (int qa = 0; qa < 2; ++qa) \
  _Pragma("unroll") \
    for (int qb = 0; qb < 2; ++qb) \
  _Pragma("unroll") \
      for (int m = 0; m < 4; ++m) \
  _Pragma("unroll") \
        for (int n = 0; n < 2; ++n) acc[qa][qb][m][n] = 0.f; \
  bf16x8 afP[4][2], afQ[4][2], bqP[2][2], bqQ[2][2]; \
  const int NT = K / 64;

// ---------------- merged QKV GEMM: 768 blocks, W = [Wq|Wk|Wv] ----------------
__global__ __launch_bounds__(512, 1) void k_gqkv(
    const unsigned short* __restrict__ A, const unsigned short* __restrict__ W,
    unsigned short* __restrict__ Qo, unsigned short* __restrict__ Ko,
    unsigned short* __restrict__ Vo,
    const float* __restrict__ sinp, const float* __restrict__ cosp)
{
  extern __shared__ unsigned short lds[];   // 131072 B
  const int id = blockIdx.x;
  const int xcd = id & 7, kk_ = id >> 3;           // 96 blocks per XCD
  const int m0 = ((xcd & 1) * 8 + kk_ / 12) * 256; // m-idx 0..15
  const int n0 = ((xcd >> 1) * 12 + kk_ % 12) * 256; // n-idx 0..47

  GEMM_PREAMBLE
  const unsigned short* srcA = A + (size_t)m0 * K;
  const unsigned short* srcB = W + (size_t)n0 * K;

  GEMM_MAIN_LOOP

  VMCNT0; LGKM0;
  const int tsel = n0 >> 12;          // 0=Q, 1=K, 2=V (block-uniform)
  if (tsel == 2) {
    // V^T [B,H,HD,S] via LDS bounce; slab [64 cols][256+pad rows].
    SBAR;
    const int n0v = n0 - 8192;
    const int b = m0 >> 11, sbase = m0 & (TS - 1);
#pragma unroll
    for (int qb = 0; qb < 2; ++qb)
#pragma unroll
      for (int n = 0; n < 2; ++n) {
        __syncthreads();
#pragma unroll
        for (int qa = 0; qa < 2; ++qa)
#pragma unroll
          for (int m = 0; m < 4; ++m) {
            int lcol = wn * 16 + lr;
            int srow = qa * 128 + wm * 64 + m * 16 + lh * 4;
            ushort4 o;
            o.x = f2bf(acc[qa][qb][m][n][0]); o.y = f2bf(acc[qa][qb][m][n][1]);
            o.z = f2bf(acc[qa][qb][m][n][2]); o.w = f2bf(acc[qa][qb][m][n][3]);
            *(ushort4*)&lds[lcol * 268 + srow] = o;
          }
        __syncthreads();
#pragma unroll
        for (int rr = 0; rr < 4; ++rr) {
          int idx = rr * 512 + t;              // 2048 chunks: 64 cols x 32 x 16B
          int dl = idx >> 5, sc = (idx & 31) * 8;
          uint4 v = *(const uint4*)&lds[dl * 268 + sc];
          int d = n0v + qb * 128 + (dl >> 4) * 32 + n * 16 + (dl & 15);
          *(uint4*)(Vo + ((size_t)((b * TH + (d >> 8)) * THD + (d & 255))) * TS + sbase + sc) = v;
        }
      }
  } else {
    unsigned short* outp = tsel ? Ko : Qo;
    const int nbase = n0 & 4095;
#pragma unroll
    for (int qa = 0; qa < 2; ++qa)
#pragma unroll
      for (int qb = 0; qb < 2; ++qb)
#pragma unroll
        for (int m = 0; m < 4; ++m)
#pragma unroll
          for (int n = 0; n < 2; ++n)
#pragma unroll
            for (int r = 0; r < 4; ++r) {
              int row = m0 + qa * 128 + wm * 64 + m * 16 + lh * 4 + r;
              int col = nbase + qb * 128 + wn * 32 + n * 16 + lr;
              float x = acc[qa][qb][m][n][r];
              float part = __shfl_xor(x, 1, 64);     // col partner d^1 = lane l^1
              int s = row & (TS - 1), b = row >> 11;
              int h = col >> 8, d = col & 255;
              float val = x;
              if (d < TROT) {
                float cc = cosp[s * TROT + d], ss = sinp[s * TROT + d];
                val = x * cc + ((d & 1) ? part : -part) * ss;
              }
              outp[((size_t)(b * TH + h) * TS + s) * THD + d] = f2bf(val);
            }
  }
}

// ---------------- output-projection GEMM: fp32 out [M,N] ----------------
__global__ __launch_bounds__(512, 1) void k_gout(
    const unsigned short* __restrict__ A, const unsigned short* __restrict__ W,
    float* __restrict__ out)
{
  extern __shared__ unsigned short lds[];   // 131072 B
  const int id = blockIdx.x;
  const int xcd = id & 7, kk_ = id >> 3;            // 32 blocks per XCD
  const int m0 = ((xcd >> 1) * 4 + (kk_ >> 3)) * 256;  // m-idx 0..15
  const int n0 = ((xcd & 1) * 8 + (kk_ & 7)) * 256;    // n-idx 0..15

  GEMM_PREAMBLE
  const unsigned short* srcA = A + (size_t)m0 * K;
  const unsigned short* srcB = W + (size_t)n0 * K;

  GEMM_MAIN_LOOP

  VMCNT0; LGKM0;
#pragma unroll
  for (int qa = 0; qa < 2; ++qa)
#pragma unroll
    for (int qb = 0; qb < 2; ++qb)
#pragma unroll
      for (int m = 0; m < 4; ++m)
#pragma unroll
        for (int n = 0; n < 2; ++n)
#pragma unroll
          for (int r = 0; r < 4; ++r) {
            int row = m0 + qa * 128 + wm * 64 + m * 16 + lh * 4 + r;
            int col = n0 + qb * 128 + wn * 32 + n * 16 + lr;
            out[(size_t)row * TD + col] = acc[qa][qb][m][n][r];
          }
}

// ---------------- causal flash attention, KVBLK=64 (r16 best-measured) ------
// log2-domain softmax (v_exp_f32 native) + last-tile-only causal masking.
__global__ __launch_bounds__(256, 2) void k_fattn(
    const unsigned short* __restrict__ Qt, const unsigned short* __restrict__ Kt,
    const unsigned short* __restrict__ Vt, unsigned short* __restrict__ O)
{
  extern __shared__ unsigned short sh[];   // K 32KB | V 32KB | Ps 9KB
  const int t = threadIdx.x, w = t >> 6, l = t & 63, lr = l & 15, lh = l >> 4;
  const int bh = blockIdx.x;
  const int qb = (gridDim.y - 1) - blockIdx.y;   // LPT: heaviest first
  const int q0 = qb * 64;
  const int jmax = qb;
  const float SC = 0.0625f * 1.44269504f;        // 1/sqrt(HD) * log2(e)

  const unsigned short* kbase = Kt + (size_t)bh * TS * THD;
  const unsigned short* vbase = Vt + (size_t)bh * THD * TS;

  const int llo = lr * 32 + ((lh ^ ((lr >> 1) & 3)) * 8);

  int koff[8], voff[8];
#pragma unroll
  for (int it = 0; it < 8; ++it) {
    int c = it * 256 + t;
    int row = (c >> 2) & 15;
    int scc = (c & 3) ^ ((row >> 1) & 3);
    koff[it] = (((c >> 9) & 3) * 16 + row) * THD + ((c >> 6) & 7) * 32 + scc * 8;
    voff[it] = (((c >> 6) & 15) * 16 + row) * TS + ((c >> 10) & 1) * 32 + scc * 8;
  }

  bf16x8 qf[8];
  const unsigned short* qp = Qt + ((size_t)bh * TS + q0 + w * 16 + lr) * THD;
#pragma unroll
  for (int kk = 0; kk < 8; ++kk) qf[kk] = *(const bf16x8*)(qp + kk * 32 + lh * 8);

  f32x4 oacc[16];
#pragma unroll
  for (int i = 0; i < 16; ++i) oacc[i] = 0.f;
  float mrow[4] = {-__builtin_inff(), -__builtin_inff(), -__builtin_inff(), -__builtin_inff()};
  float lrow[4] = {0.f, 0.f, 0.f, 0.f};   // lane-partial denominators

#pragma unroll
  for (int it = 0; it < 8; ++it) gld16(kbase + koff[it], &sh[(it*256 + t) * 8]);
#pragma unroll
  for (int it = 0; it < 8; ++it) gld16(vbase + voff[it], &sh[16384 + (it*256 + t) * 8]);

  for (int j = 0; j <= jmax; ++j) {
    const bool nx = (j < jmax);
    VMCNT8; SBAR; SCHED0;

    f32x4 sacc[4];
#pragma unroll
    for (int nt = 0; nt < 4; ++nt) sacc[nt] = 0.f;
    PRIO1;
#pragma unroll
    for (int kk = 0; kk < 8; ++kk)
#pragma unroll
      for (int nt = 0; nt < 4; ++nt) {
        bf16x8 kf = *(const bf16x8*)&sh[(nt*8 + kk)*512 + llo];
        sacc[nt] = __builtin_amdgcn_mfma_f32_16x16x32_bf16(qf[kk], kf, sacc[nt], 0, 0, 0);
      }
    PRIO0;
    LGKM0; SBAR; SCHED0;
    if (nx) {
      const unsigned short* kj = kbase + (size_t)(j + 1) * 64 * THD;
#pragma unroll
      for (int it = 0; it < 8; ++it) gld16(kj + koff[it], &sh[(it*256 + t) * 8]);
    }

    // ---- online softmax (log2 domain; mask only on diagonal tile) ----
    float p[4][4];
    const int qrow0 = q0 + w * 16 + lh * 4;
    if (j == jmax) {
#pragma unroll
      for (int nt = 0; nt < 4; ++nt) {
        int kpos = j * 64 + nt * 16 + lr;
#pragma unroll
        for (int r = 0; r < 4; ++r) {
          float sv = sacc[nt][r] * SC;
          if (kpos > qrow0 + r) sv = -__builtin_inff();
          p[nt][r] = sv;
        }
      }
    } else {
#pragma unroll
      for (int nt = 0; nt < 4; ++nt)
#pragma unroll
        for (int r = 0; r < 4; ++r)
          p[nt][r] = sacc[nt][r] * SC;
    }
    float lmax[4];
#pragma unroll
    for (int r = 0; r < 4; ++r)
      lmax[r] = fmaxf(fmaxf(p[0][r], p[1][r]), fmaxf(p[2][r], p[3][r]));
    float g = fmaxf(fmaxf(lmax[0] - mrow[0], lmax[1] - mrow[1]),
                    fmaxf(lmax[2] - mrow[2], lmax[3] - mrow[3]));
    if (__any(g > 11.5416f)) {              // 8 * log2(e): rare rescale path
      float tmax[4] = {lmax[0], lmax[1], lmax[2], lmax[3]};
#pragma unroll
      for (int off = 1; off < 16; off <<= 1)
#pragma unroll
        for (int r = 0; r < 4; ++r) tmax[r] = fmaxf(tmax[r], __shfl_xor(tmax[r], off, 64));
      float alpha[4];
#pragma unroll
      for (int r = 0; r < 4; ++r) {
        float mn = fmaxf(mrow[r], tmax[r]);
        alpha[r] = EXP2(mrow[r] - mn);
        mrow[r] = mn;
        lrow[r] *= alpha[r];
      }
#pragma unroll
      for (int i = 0; i < 16; ++i)
#pragma unroll
        for (int r = 0; r < 4; ++r) oacc[i][r] *= alpha[r];
    }
#pragma unroll
    for (int r = 0; r < 4; ++r) {
      float pe0 = EXP2(p[0][r] - mrow[r]);
      float pe1 = EXP2(p[1][r] - mrow[r]);
      float pe2 = EXP2(p[2][r] - mrow[r]);
      float pe3 = EXP2(p[3][r] - mrow[r]);
      p[0][r] = pe0; p[1][r] = pe1; p[2][r] = pe2; p[3][r] = pe3;
      lrow[r] += (pe0 + pe1) + (pe2 + pe3);
    }

    const int wb = 32768 + w * 1152;
#pragma unroll
    for (int nt = 0; nt < 4; ++nt)
#pragma unroll
      for (int r = 0; r < 4; ++r)
        sh[wb + (lh*4 + r)*72 + nt*16 + lr] = f2bf(p[nt][r]);
    bf16x8 pfr0 = *(const bf16x8*)&sh[wb + lr*72 + lh*8];
    bf16x8 pfr1 = *(const bf16x8*)&sh[wb + lr*72 + 32 + lh*8];

    if (nx) { VMCNT8; } else { VMCNT0; }
    SBAR; SCHED0;
    PRIO1;
#pragma unroll
    for (int dt = 0; dt < 16; ++dt) {
      bf16x8 vf = *(const bf16x8*)&sh[16384 + dt*512 + llo];
      oacc[dt] = __builtin_amdgcn_mfma_f32_16x16x32_bf16(pfr0, vf, oacc[dt], 0, 0, 0);
    }
#pragma unroll
    for (int dt = 0; dt < 16; ++dt) {
      bf16x8 vf = *(const bf16x8*)&sh[16384 + (16 + dt)*512 + llo];
      oacc[dt] = __builtin_amdgcn_mfma_f32_16x16x32_bf16(pfr1, vf, oacc[dt], 0, 0, 0);
    }
    PRIO0;
    LGKM0; SBAR; SCHED0;
    if (nx) {
      const unsigned short* vj = vbase + (size_t)(j + 1) * 64;
#pragma unroll
      for (int it = 0; it < 8; ++it) gld16(vj + voff[it], &sh[16384 + (it*256 + t) * 8]);
    }
  }

  // epilogue: reduce lane-partial denominators once, then write O
#pragma unroll
  for (int off = 1; off < 16; off <<= 1)
#pragma unroll
    for (int r = 0; r < 4; ++r) lrow[r] += __shfl_xor(lrow[r], off, 64);

  const int b = bh >> 4, h = bh & 15;
  float inv[4];
#pragma unroll
  for (int r = 0; r < 4; ++r) inv[r] = 1.f / lrow[r];
#pragma unroll
  for (int dt = 0; dt < 16; ++dt)
#pragma unroll
    for (int r = 0; r < 4; ++r) {
      int s = q0 + w * 16 + lh * 4 + r;
      O[((size_t)(b * TS + s) * TH + h) * THD + dt * 16 + lr] = f2bf(oacc[dt][r] * inv[r]);
    }
}

// ---------------- launch ----------------
extern "C" void kernel_launch(void* const* d_in, const int* in_sizes, int n_in,
                              void* d_out, int out_size, void* d_ws, size_t ws_size,
                              hipStream_t stream) {
  const float* hs   = (const float*)d_in[0];
  const float* sinp = (const float*)d_in[1];
  const float* cosp = (const float*)d_in[2];
  const float* Wq   = (const float*)d_in[3];
  const float* Wk   = (const float*)d_in[4];
  const float* Wv   = (const float*)d_in[5];
  const float* Wo   = (const float*)d_in[6];

  const size_t NE = (size_t)TM * TD;
  const size_t BYTES = NE * 2;
  char* ws = (char*)d_ws;
  unsigned short* hsb = (unsigned short*)(ws + 0*BYTES);
  unsigned short* Wqb = (unsigned short*)(ws + 1*BYTES);  // [Wq|Wk|Wv] contiguous
  unsigned short* Wob = (unsigned short*)(ws + 4*BYTES);
  unsigned short* Qt  = (unsigned short*)(ws + 5*BYTES);  // [B,H,S,HD]
  unsigned short* Ktb = (unsigned short*)(ws + 6*BYTES);  // [B,H,S,HD]
  unsigned short* Vtb = (unsigned short*)(ws + 7*BYTES);  // [B,H,HD,S]
  unsigned short* Ob  = (unsigned short*)(ws + 8*BYTES);  // [B,S,H,HD] == [M,D]

  k_cvt5<<<81920, 256, 0, stream>>>(hs, Wq, Wk, Wv, Wo, hsb);

  k_gqkv<<<768, 512, 131072, stream>>>(hsb, Wqb, Qt, Ktb, Vtb, sinp, cosp);

  k_fattn<<<dim3(TB*TH, TS/64), 256, 74752, stream>>>(Qt, Ktb, Vtb, Ob);

  k_gout<<<256, 512, 131072, stream>>>(Ob, Wob, (float*)d_out);
}